// Round 15
// baseline (1916.752 us; speedup 1.0000x reference)
//
#include <hip/hip_runtime.h>
#include <math.h>

#define DIM 512
#define NCLS 100
#define NS 2048
#define DD (DIM*DIM)
#define SHRINKV 1e-4f
#define FGRID 256

typedef short bf16x8 __attribute__((ext_vector_type(8)));
typedef short s16x4 __attribute__((ext_vector_type(4)));
typedef float f32x4 __attribute__((ext_vector_type(4)));

static __device__ __forceinline__ short f2bf(float f) {
  unsigned int u = __float_as_uint(f);
  u += 0x7FFFu + ((u >> 16) & 1u);   // round-to-nearest-even
  return (short)(u >> 16);
}

// Software grid barrier (sense-reversal). bar[0]=arrival count, bar[1]=sense.
// Both zeroed by hipMemsetAsync EVERY kernel_launch (graph-replay safe).
// Requires all FGRID blocks co-resident: grid=256=CU count, 2 WG/CU capacity.
static __device__ __forceinline__ void gsync(int* bar, int& ls) {
  __syncthreads();
  if (threadIdx.x == 0) {
    ls ^= 1;
    __threadfence();
    if (atomicAdd(&bar[0], 1) == FGRID - 1) {
      bar[0] = 0;
      __threadfence();
      atomicExch(&bar[1], ls);
    } else {
      while (atomicAdd(&bar[1], 0) != ls) __builtin_amdgcn_s_sleep(2);
    }
    __threadfence();
  }
  __syncthreads();
}

// Build M_k = (1-sh)*(0.5*(SigmaK_k+Sigma)) + sh*I ; accumulate ||RegSigma||_F^2
__global__ __launch_bounds__(256) void prep_kernel(const float* __restrict__ SigmaK,
                                                   const float* __restrict__ Sigma,
                                                   float* __restrict__ M,
                                                   float* __restrict__ aux) {
  int b = blockIdx.x;
  int k = b >> 2, chunk = b & 3;
  const float* Sk = SigmaK + (size_t)k * DD;
  float* Mk = M + (size_t)k * DD;
  int base0 = chunk << 16;
  float fro = 0.f;
  const float oms = 1.0f - SHRINKV;
  for (int it = 0; it < 64; ++it) {
    int idx = base0 + (it << 10) + (threadIdx.x << 2);
    float4 a = *(const float4*)(Sk + idx);
    float4 g = *(const float4*)(Sigma + idx);
    int r = idx >> 9, c = idx & 511;
    float4 reg;
    reg.x = 0.5f*(a.x + g.x); reg.y = 0.5f*(a.y + g.y);
    reg.z = 0.5f*(a.z + g.z); reg.w = 0.5f*(a.w + g.w);
    fro += reg.x*reg.x + reg.y*reg.y + reg.z*reg.z + reg.w*reg.w;
    float4 m;
    m.x = oms*reg.x + ((r == c + 0) ? SHRINKV : 0.f);
    m.y = oms*reg.y + ((r == c + 1) ? SHRINKV : 0.f);
    m.z = oms*reg.z + ((r == c + 2) ? SHRINKV : 0.f);
    m.w = oms*reg.w + ((r == c + 3) ? SHRINKV : 0.f);
    *(float4*)(Mk + idx) = m;
  }
  __shared__ float red[4];
  int lane = threadIdx.x & 63, w = threadIdx.x >> 6;
  for (int o = 32; o > 0; o >>= 1) fro += __shfl_down(fro, o);
  if (lane == 0) red[w] = fro;
  __syncthreads();
  if (threadIdx.x == 0) atomicAdd(&aux[1 + k], red[0] + red[1] + red[2] + red[3]);
}

// Single-wave diag factor + triangular inverse for panel at p0 (no barriers).
static __device__ __forceinline__ void fdiag_dev(float* __restrict__ Mk,
                                                 short* __restrict__ Wk,
                                                 int p0, int lane,
                                                 float* __restrict__ Llds) {
  float row[64];
  const float* src = Mk + (size_t)(p0 + lane) * DIM + p0;
  #pragma unroll
  for (int c4 = 0; c4 < 64; c4 += 4) {
    float4 v = *(const float4*)(src + c4);
    row[c4] = v.x; row[c4+1] = v.y; row[c4+2] = v.z; row[c4+3] = v.w;
  }
  #pragma unroll
  for (int j = 0; j < 64; ++j) {
    float diagv = __shfl(row[j], j);
    float dv = sqrtf(diagv);
    float rinv = 1.0f / dv;
    float myLj = row[j] * rinv;
    row[j] = myLj;
    #pragma unroll
    for (int c = j + 1; c < 64; ++c)
      row[c] = fmaf(-myLj, __shfl(myLj, c), row[c]);
  }
  #pragma unroll
  for (int c = 0; c < 64; ++c)
    Llds[lane * 68 + c] = (c <= lane) ? row[c] : 0.f;
  float w[64];
  #pragma unroll
  for (int r = 0; r < 64; ++r) {
    float s = 0.f;
    #pragma unroll
    for (int kk = 0; kk + 4 <= r; kk += 4) {
      float4 lv = *(const float4*)(Llds + r*68 + kk);
      s += lv.x*w[kk] + lv.y*w[kk+1] + lv.z*w[kk+2] + lv.w*w[kk+3];
    }
    #pragma unroll
    for (int kk = r & ~3; kk < r; ++kk) s += Llds[r*68 + kk] * w[kk];
    float rhs = ((r == lane) ? 1.0f : 0.0f) - s;
    w[r] = rhs / Llds[r*68 + r];   // exact 0 for r < lane
  }
  #pragma unroll
  for (int r = 0; r < 64; ++r) {
    Mk[(size_t)(p0 + r)*DIM + p0 + lane] = w[r];
    Wk[(size_t)(p0 + r)*DIM + p0 + lane] = f2bf(w[r]);
  }
}

// One persistent kernel for the ENTIRE factorization + inverse sweep.
// 256 WGs (1/CU, co-resident), grid-stride items, software gsync between
// phases. Schedule identical to verified rounds 10/12:
//   fdiag(0)
//   for p: phaseA = trsm(p) [+ (p+1,p+1) fold in lead] + sweeprow(p)
//          phaseB = syrkR(p) (pairs except (p+1,p+1)) || fdiag(p+1)
__global__ __launch_bounds__(256) void factor_kernel(float* __restrict__ M,
                                                     short* __restrict__ Wb,
                                                     int* __restrict__ bar) {
  __shared__ float SA[2][64 * 68];
  __shared__ float SB[2][64 * 68];
  const int wgid = blockIdx.x;
  const int tid = threadIdx.x;
  const int ty = tid >> 4, tx = tid & 15;
  const int sr = tid >> 2, sq = (tid & 3) << 4;
  int ls = 0;

  // ---- fdiag(0) ----
  for (int w = wgid; w < NCLS; w += FGRID) {
    __syncthreads();
    if (tid < 64)
      fdiag_dev(M + (size_t)w * DD, Wb + (size_t)w * DD, 0, tid, SA[0]);
  }
  __threadfence();
  gsync(bar, ls);

  for (int p = 0; p < 8; ++p) {
    const int n = 7 - p;
    const int p0 = p << 6;
    // ================= phase A: trsm + fold + sweeprow =================
    for (int w = wgid; w < NCLS * 7; w += FGRID) {
      int cls = w / 7, r = w % 7;
      float* Mk = M + (size_t)cls * DD;
      short* Wk = Wb + (size_t)cls * DD;
      __syncthreads();   // LDS reuse across items
      if (r < n) {
        // ---- TRSM: L_ip = A_ip * inv(p)^T ----
        int i = p + 1 + r;
        {
          const float* a = Mk + (size_t)((i << 6) + sr)*DIM + p0 + sq;
          const float* b = Mk + (size_t)(p0 + sr)*DIM + p0 + sq;   // inv(p)
          #pragma unroll
          for (int t4 = 0; t4 < 4; ++t4) {
            float4 va = *(const float4*)(a + 4*t4);
            SA[0][(sq+4*t4+0)*68+sr]=va.x; SA[0][(sq+4*t4+1)*68+sr]=va.y;
            SA[0][(sq+4*t4+2)*68+sr]=va.z; SA[0][(sq+4*t4+3)*68+sr]=va.w;
            float4 vb = *(const float4*)(b + 4*t4);
            SA[1][(sq+4*t4+0)*68+sr]=vb.x; SA[1][(sq+4*t4+1)*68+sr]=vb.y;
            SA[1][(sq+4*t4+2)*68+sr]=vb.z; SA[1][(sq+4*t4+3)*68+sr]=vb.w;
          }
        }
        __syncthreads();
        float acc[4][4];
        #pragma unroll
        for (int a2 = 0; a2 < 4; ++a2)
          #pragma unroll
          for (int b2 = 0; b2 < 4; ++b2) acc[a2][b2] = 0.f;
        #pragma unroll 16
        for (int m = 0; m < 64; ++m) {
          float4 av = *(const float4*)(&SA[0][m*68 + (ty << 2)]);
          float4 bv = *(const float4*)(&SA[1][m*68 + (tx << 2)]);
          float a4[4] = {av.x, av.y, av.z, av.w};
          float b4[4] = {bv.x, bv.y, bv.z, bv.w};
          #pragma unroll
          for (int ir = 0; ir < 4; ++ir)
            #pragma unroll
            for (int ic = 0; ic < 4; ++ic) acc[ir][ic] += a4[ir] * b4[ic];
        }
        #pragma unroll
        for (int q = 0; q < 4; ++q) {
          float4 v; v.x = acc[q][0]; v.y = acc[q][1]; v.z = acc[q][2]; v.w = acc[q][3];
          *(float4*)(Mk + (size_t)((i << 6) + (ty << 2) + q)*DIM + p0 + (tx << 2)) = v;
        }
        if (r == 0) {
          // fold syrk of (p+1,p+1): C -= L*L^T  (L = acc, in-register)
          __syncthreads();
          #pragma unroll
          for (int q = 0; q < 4; ++q)
            #pragma unroll
            for (int cc = 0; cc < 4; ++cc)
              SA[0][((tx << 2) + cc)*68 + (ty << 2) + q] = acc[q][cc];   // [m][r]=L[r][m]
          __syncthreads();
          float s2[4][4];
          #pragma unroll
          for (int a2 = 0; a2 < 4; ++a2)
            #pragma unroll
            for (int b2 = 0; b2 < 4; ++b2) s2[a2][b2] = 0.f;
          #pragma unroll 16
          for (int m = 0; m < 64; ++m) {
            float4 av = *(const float4*)(&SA[0][m*68 + (ty << 2)]);
            float4 bv = *(const float4*)(&SA[0][m*68 + (tx << 2)]);
            float a4[4] = {av.x, av.y, av.z, av.w};
            float b4[4] = {bv.x, bv.y, bv.z, bv.w};
            #pragma unroll
            for (int ir = 0; ir < 4; ++ir)
              #pragma unroll
              for (int ic = 0; ic < 4; ++ic) s2[ir][ic] += a4[ir] * b4[ic];
          }
          int d0 = (p + 1) << 6;
          #pragma unroll
          for (int q = 0; q < 4; ++q) {
            float* dst = Mk + (size_t)(d0 + (ty << 2) + q)*DIM + d0 + (tx << 2);
            float4 v = *(const float4*)dst;
            v.x -= s2[q][0]; v.y -= s2[q][1]; v.z -= s2[q][2]; v.w -= s2[q][3];
            *(float4*)dst = v;
          }
        }
      } else {
        // ---- sweeprow: W_pj = -W_pp * sum_{k=j}^{p-1} L_pk W_kj ----
        int j = r - n;
        auto stageLW = [&](int k, int buf) {
          const float* a = Mk + (size_t)(p0 + sr)*DIM + (k << 6) + sq;          // L_pk
          const float* b = Mk + (size_t)((j << 6) + sr)*DIM + (k << 6) + sq;    // W_kj
          #pragma unroll
          for (int t4 = 0; t4 < 4; ++t4) {
            float4 va = *(const float4*)(a + 4*t4);
            SA[buf][(sq+4*t4+0)*68+sr]=va.x; SA[buf][(sq+4*t4+1)*68+sr]=va.y;
            SA[buf][(sq+4*t4+2)*68+sr]=va.z; SA[buf][(sq+4*t4+3)*68+sr]=va.w;
            *(float4*)(&SB[buf][sr*68 + sq + 4*t4]) = *(const float4*)(b + 4*t4);
          }
        };
        float acc[4][4];
        #pragma unroll
        for (int a = 0; a < 4; ++a)
          #pragma unroll
          for (int b = 0; b < 4; ++b) acc[a][b] = 0.f;
        stageLW(j, 0);
        __syncthreads();
        int cur = 0;
        for (int k = j; k < p; ++k) {
          if (k + 1 < p) stageLW(k + 1, cur ^ 1);
          #pragma unroll 16
          for (int m = 0; m < 64; ++m) {
            float4 av = *(const float4*)(&SA[cur][m*68 + (ty << 2)]);
            float4 bv = *(const float4*)(&SB[cur][m*68 + (tx << 2)]);
            float a4[4] = {av.x, av.y, av.z, av.w};
            float b4[4] = {bv.x, bv.y, bv.z, bv.w};
            #pragma unroll
            for (int ir = 0; ir < 4; ++ir)
              #pragma unroll
              for (int ic = 0; ic < 4; ++ic) acc[ir][ic] += a4[ir] * b4[ic];
          }
          __syncthreads();
          cur ^= 1;
        }
        #pragma unroll
        for (int q = 0; q < 4; ++q) {
          float4 v; v.x = acc[q][0]; v.y = acc[q][1]; v.z = acc[q][2]; v.w = acc[q][3];
          *(float4*)(&SB[0][((ty << 2) + q)*68 + (tx << 2)]) = v;
        }
        {
          const float* a = Mk + (size_t)(p0 + sr)*DIM + p0 + sq;   // W_pp = inv(p)
          #pragma unroll
          for (int t4 = 0; t4 < 4; ++t4) {
            float4 va = *(const float4*)(a + 4*t4);
            SA[0][(sq+4*t4+0)*68+sr]=va.x; SA[0][(sq+4*t4+1)*68+sr]=va.y;
            SA[0][(sq+4*t4+2)*68+sr]=va.z; SA[0][(sq+4*t4+3)*68+sr]=va.w;
          }
        }
        __syncthreads();
        float r2[4][4];
        #pragma unroll
        for (int a = 0; a < 4; ++a)
          #pragma unroll
          for (int b = 0; b < 4; ++b) r2[a][b] = 0.f;
        #pragma unroll 16
        for (int m = 0; m < 64; ++m) {
          float4 av = *(const float4*)(&SA[0][m*68 + (ty << 2)]);
          float4 bv = *(const float4*)(&SB[0][m*68 + (tx << 2)]);
          float a4[4] = {av.x, av.y, av.z, av.w};
          float b4[4] = {bv.x, bv.y, bv.z, bv.w};
          #pragma unroll
          for (int ir = 0; ir < 4; ++ir)
            #pragma unroll
            for (int ic = 0; ic < 4; ++ic) r2[ir][ic] += a4[ir] * b4[ic];
        }
        #pragma unroll
        for (int q = 0; q < 4; ++q) {
          int a = (ty << 2) + q;
          float4 v; v.x = -r2[q][0]; v.y = -r2[q][1]; v.z = -r2[q][2]; v.w = -r2[q][3];
          *(float4*)(Mk + (size_t)((j << 6) + a)*DIM + p0 + (tx << 2)) = v;   // upper (j,p)
          s16x4 h;
          h[0] = f2bf(v.x); h[1] = f2bf(v.y); h[2] = f2bf(v.z); h[3] = f2bf(v.w);
          *(s16x4*)(Wk + (size_t)(p0 + a)*DIM + (j << 6) + (tx << 2)) = h;    // bf16 (p,j)
        }
      }
    }
    __threadfence();
    gsync(bar, ls);
    // ================= phase B: syrkR || fdiag(p+1) =================
    if (p < 7) {
      const int T = n * (n + 1) / 2;
      const int nsyrk = NCLS * (T - 1);
      const int nB = nsyrk + NCLS;
      for (int w = wgid; w < nB; w += FGRID) {
        __syncthreads();
        if (w >= nsyrk) {
          int cls = w - nsyrk;
          if (tid < 64)
            fdiag_dev(M + (size_t)cls * DD, Wb + (size_t)cls * DD,
                      (p + 1) << 6, tid, SA[0]);
        } else {
          int cls = w / (T - 1);
          int t = w % (T - 1) + 1;   // skip (p+1,p+1), folded in phase A
          int bi = 0;
          while (t > bi) { t -= bi + 1; ++bi; }
          int i = p + 1 + bi, j = p + 1 + t;
          float* Mk = M + (size_t)cls * DD;
          {
            const float* a = Mk + (size_t)((i << 6) + sr)*DIM + p0 + sq;
            const float* b = Mk + (size_t)((j << 6) + sr)*DIM + p0 + sq;
            #pragma unroll
            for (int t4 = 0; t4 < 4; ++t4) {
              float4 va = *(const float4*)(a + 4*t4);
              SA[0][(sq+4*t4+0)*68+sr]=va.x; SA[0][(sq+4*t4+1)*68+sr]=va.y;
              SA[0][(sq+4*t4+2)*68+sr]=va.z; SA[0][(sq+4*t4+3)*68+sr]=va.w;
              float4 vb = *(const float4*)(b + 4*t4);
              SA[1][(sq+4*t4+0)*68+sr]=vb.x; SA[1][(sq+4*t4+1)*68+sr]=vb.y;
              SA[1][(sq+4*t4+2)*68+sr]=vb.z; SA[1][(sq+4*t4+3)*68+sr]=vb.w;
            }
          }
          __syncthreads();
          float acc[4][4];
          #pragma unroll
          for (int a2 = 0; a2 < 4; ++a2)
            #pragma unroll
            for (int b2 = 0; b2 < 4; ++b2) acc[a2][b2] = 0.f;
          #pragma unroll 16
          for (int m = 0; m < 64; ++m) {
            float4 av = *(const float4*)(&SA[0][m*68 + (ty << 2)]);
            float4 bv = *(const float4*)(&SA[1][m*68 + (tx << 2)]);
            float a4[4] = {av.x, av.y, av.z, av.w};
            float b4[4] = {bv.x, bv.y, bv.z, bv.w};
            #pragma unroll
            for (int ir = 0; ir < 4; ++ir)
              #pragma unroll
              for (int ic = 0; ic < 4; ++ic) acc[ir][ic] += a4[ir] * b4[ic];
          }
          #pragma unroll
          for (int q = 0; q < 4; ++q) {
            float* dst = Mk + (size_t)((i << 6) + (ty << 2) + q)*DIM + (j << 6) + (tx << 2);
            float4 v = *(const float4*)dst;
            v.x -= acc[q][0]; v.y -= acc[q][1]; v.z -= acc[q][2]; v.w -= acc[q][3];
            *(float4*)dst = v;
          }
        }
      }
      __threadfence();
      gsync(bar, ls);
    }
  }
}

// scores via bf16 MFMA. W tiles staged via global_load_lds into a 4-buffer
// ring, depth-2 pipeline with counted vmcnt + raw barriers (T3+T4).
__global__ __launch_bounds__(256) void score_kernel(const float* __restrict__ X,
                                                    const float* __restrict__ muK,
                                                    const float* __restrict__ cK,
                                                    const short* __restrict__ W,
                                                    const float* __restrict__ aux,
                                                    float* __restrict__ out) {
  __shared__ __align__(16) char WB4[4][8192];
  __shared__ float sred[4];
  int bid = blockIdx.x;
  int wg = ((bid & 7) * 400) + (bid >> 3);   // XCD swizzle (3200 = 8*400)
  int kc = wg >> 5;
  int n0 = (wg & 31) << 6;
  int tid = threadIdx.x;
  int lane = tid & 63, wv = tid >> 6;
  const short* Wk = W + (size_t)kc * DD;
  const float* mu = muK + (size_t)kc * DIM;
  int r16 = lane & 15;
  int k8 = (lane >> 4) << 3;
  int arow = (wv << 4) + r16;

  int lrow = lane >> 3;
  int lcolel = ((lane & 7) ^ lrow) << 3;

  constexpr int SJT[36] = {0,1,1, 2,3,2,3,2,3,3, 4,5,4,5,4,5,4,5,4,5,5,
                           6,7,6,7,6,7,6,7,6,7,6,7,6,7,7};
  constexpr int SDC[36] = {0,0,1, 0,0,1,1,2,2,3, 0,0,1,1,2,2,3,3,4,4,5,
                           0,0,1,1,2,2,3,3,4,4,5,5,6,6,7};

  bf16x8 af[8][2];
  #pragma unroll
  for (int dc = 0; dc < 8; ++dc) {
    #pragma unroll
    for (int ks = 0; ks < 2; ++ks) {
      int col = (dc << 6) + (ks << 5) + k8;
      const float* xp = X + (size_t)(n0 + arow)*DIM + col;
      float4 x0 = *(const float4*)xp;
      float4 x1 = *(const float4*)(xp + 4);
      float4 m0 = *(const float4*)(mu + col);
      float4 m1 = *(const float4*)(mu + col + 4);
      bf16x8 h;
      h[0]=f2bf(x0.x-m0.x); h[1]=f2bf(x0.y-m0.y); h[2]=f2bf(x0.z-m0.z); h[3]=f2bf(x0.w-m0.w);
      h[4]=f2bf(x1.x-m1.x); h[5]=f2bf(x1.y-m1.y); h[6]=f2bf(x1.z-m1.z); h[7]=f2bf(x1.w-m1.w);
      af[dc][ks] = h;
    }
  }

  auto issue = [&](int s) {
    const int b = s & 3;
    const int rbase = SJT[s] << 6;
    const int cc = (SDC[s] << 6) + lcolel;
    #pragma unroll
    for (int q = 0; q < 2; ++q) {
      const short* g = Wk + (size_t)(rbase + (q << 5) + (wv << 3) + lrow)*DIM + cc;
      __builtin_amdgcn_global_load_lds(
          (const __attribute__((address_space(1))) void*)g,
          (__attribute__((address_space(3))) void*)(WB4[b] + (q << 12) + (wv << 10)),
          16, 0, 0);
    }
  };

  float qp[4] = {0.f, 0.f, 0.f, 0.f};
  f32x4 acc[2][4];
  #pragma unroll
  for (int a = 0; a < 2; ++a)
    #pragma unroll
    for (int jj = 0; jj < 4; ++jj) { acc[a][jj][0]=0.f; acc[a][jj][1]=0.f; acc[a][jj][2]=0.f; acc[a][jj][3]=0.f; }

  issue(0);
  issue(1);
  #pragma unroll
  for (int s = 0; s < 36; ++s) {
    const int jt = SJT[s], dc = SDC[s];
    if (s + 2 < 36) issue(s + 2);
    if (s < 34)      asm volatile("s_waitcnt vmcnt(4)" ::: "memory");
    else if (s == 34) asm volatile("s_waitcnt vmcnt(2)" ::: "memory");
    else              asm volatile("s_waitcnt vmcnt(0)" ::: "memory");
    __builtin_amdgcn_s_barrier();
    __builtin_amdgcn_sched_barrier(0);
    __builtin_amdgcn_s_setprio(1);
    #pragma unroll
    for (int ks = 0; ks < 2; ++ks) {
      #pragma unroll
      for (int jj = 0; jj < 4; ++jj) {
        int brow = (jj << 4) + r16;
        bf16x8 bfr = *(const bf16x8*)((const char*)WB4[s & 3] +
                     (((brow << 7) + (((ks << 5) + k8) << 1)) ^ ((brow & 7) << 4)));
        acc[jt & 1][jj] = __builtin_amdgcn_mfma_f32_16x16x32_bf16(af[dc][ks], bfr, acc[jt & 1][jj], 0, 0, 0);
      }
    }
    __builtin_amdgcn_s_setprio(0);
    if (s == 2 || s == 9 || s == 20 || s == 35) {
      #pragma unroll
      for (int a = 0; a < 2; ++a)
        #pragma unroll
        for (int jj = 0; jj < 4; ++jj)
          #pragma unroll
          for (int r = 0; r < 4; ++r) {
            float y = acc[a][jj][r]; qp[r] += y * y;
            acc[a][jj][r] = 0.f;
          }
    }
  }
  #pragma unroll
  for (int r = 0; r < 4; ++r) {
    qp[r] += __shfl_xor(qp[r], 1);
    qp[r] += __shfl_xor(qp[r], 2);
    qp[r] += __shfl_xor(qp[r], 4);
    qp[r] += __shfl_xor(qp[r], 8);
  }
  {
    float v = (tid < NCLS) ? cK[tid] : 0.f;
    #pragma unroll
    for (int o = 32; o > 0; o >>= 1) v += __shfl_xor(v, o);
    if (lane == 0) sred[wv] = v;
  }
  __syncthreads();
  float sumck = sred[0] + sred[1] + sred[2] + sred[3];
  float ck = cK[kc];
  float base;
  if (ck == 0.f) base = -INFINITY;
  else base = logf(ck) - logf(sumck) - 0.25f * logf(aux[1 + kc]);
  if ((lane & 15) == 0) {
    int nbase = n0 + (wv << 4) + ((lane >> 4) << 2);
    #pragma unroll
    for (int r = 0; r < 4; ++r)
      out[(size_t)(nbase + r)*NCLS + kc] = base - 0.5f * qp[r];
  }
}

extern "C" void kernel_launch(void* const* d_in, const int* in_sizes, int n_in,
                              void* d_out, int out_size, void* d_ws, size_t ws_size,
                              hipStream_t stream) {
  (void)in_sizes; (void)n_in; (void)out_size; (void)ws_size;
  const float* X      = (const float*)d_in[0];
  const float* muK    = (const float*)d_in[1];
  const float* SigmaK = (const float*)d_in[2];
  const float* Sigma  = (const float*)d_in[3];
  const float* cK     = (const float*)d_in[4];
  float* out = (float*)d_out;
  char* ws = (char*)d_ws;
  float* M   = (float*)ws;                                   // 104857600 B
  short* W   = (short*)(ws + (size_t)NCLS * DD * 4);         //  52428800 B
  float* aux = (float*)(ws + (size_t)NCLS * DD * 6);         // fro^2 etc.
  int*   bar = (int*)(aux + 128);                            // gsync state

  (void)hipMemsetAsync(aux, 0, 132 * sizeof(float), stream); // aux + bar
  prep_kernel<<<400, 256, 0, stream>>>(SigmaK, Sigma, M, aux);
  factor_kernel<<<FGRID, 256, 0, stream>>>(M, W, bar);
  score_kernel<<<NCLS * 32, 256, 0, stream>>>(X, muK, cK, W, aux, out);
}

// Round 16
// 1700.082 us; speedup vs baseline: 1.1274x; 1.1274x over previous
//
#include <hip/hip_runtime.h>
#include <math.h>

#define DIM 512
#define NCLS 100
#define NS 2048
#define DD (DIM*DIM)
#define SHRINKV 1e-4f

typedef short bf16x8 __attribute__((ext_vector_type(8)));
typedef short s16x4 __attribute__((ext_vector_type(4)));
typedef float f32x4 __attribute__((ext_vector_type(4)));

static __device__ __forceinline__ short f2bf(float f) {
  unsigned int u = __float_as_uint(f);
  u += 0x7FFFu + ((u >> 16) & 1u);   // round-to-nearest-even
  return (short)(u >> 16);
}

// Build M_k = (1-sh)*(0.5*(SigmaK_k+Sigma)) + sh*I ; accumulate ||RegSigma||_F^2
__global__ __launch_bounds__(256) void prep_kernel(const float* __restrict__ SigmaK,
                                                   const float* __restrict__ Sigma,
                                                   float* __restrict__ M,
                                                   float* __restrict__ aux) {
  int b = blockIdx.x;
  int k = b >> 2, chunk = b & 3;
  const float* Sk = SigmaK + (size_t)k * DD;
  float* Mk = M + (size_t)k * DD;
  int base0 = chunk << 16;
  float fro = 0.f;
  const float oms = 1.0f - SHRINKV;
  for (int it = 0; it < 64; ++it) {
    int idx = base0 + (it << 10) + (threadIdx.x << 2);
    float4 a = *(const float4*)(Sk + idx);
    float4 g = *(const float4*)(Sigma + idx);
    int r = idx >> 9, c = idx & 511;
    float4 reg;
    reg.x = 0.5f*(a.x + g.x); reg.y = 0.5f*(a.y + g.y);
    reg.z = 0.5f*(a.z + g.z); reg.w = 0.5f*(a.w + g.w);
    fro += reg.x*reg.x + reg.y*reg.y + reg.z*reg.z + reg.w*reg.w;
    float4 m;
    m.x = oms*reg.x + ((r == c + 0) ? SHRINKV : 0.f);
    m.y = oms*reg.y + ((r == c + 1) ? SHRINKV : 0.f);
    m.z = oms*reg.z + ((r == c + 2) ? SHRINKV : 0.f);
    m.w = oms*reg.w + ((r == c + 3) ? SHRINKV : 0.f);
    *(float4*)(Mk + idx) = m;
  }
  __shared__ float red[4];
  int lane = threadIdx.x & 63, w = threadIdx.x >> 6;
  for (int o = 32; o > 0; o >>= 1) fro += __shfl_down(fro, o);
  if (lane == 0) red[w] = fro;
  __syncthreads();
  if (threadIdx.x == 0) atomicAdd(&aux[1 + k], red[0] + red[1] + red[2] + red[3]);
}

// Single-wave diag factor + triangular inverse (no barriers). Writes inv to
// M(p,p) f32 + W(p,p) bf16 + invT[m*68+c] = inv[c][m] (LDS, GEMM B-operand).
static __device__ __forceinline__ void fdiag_dev(float* __restrict__ Mk,
                                                 short* __restrict__ Wk,
                                                 int p0, int lane,
                                                 float* __restrict__ Llds,
                                                 float* __restrict__ invT) {
  float row[64];
  const float* src = Mk + (size_t)(p0 + lane) * DIM + p0;
  #pragma unroll
  for (int c4 = 0; c4 < 64; c4 += 4) {
    float4 v = *(const float4*)(src + c4);
    row[c4] = v.x; row[c4+1] = v.y; row[c4+2] = v.z; row[c4+3] = v.w;
  }
  #pragma unroll
  for (int j = 0; j < 64; ++j) {
    float diagv = __shfl(row[j], j);
    float dv = sqrtf(diagv);
    float rinv = 1.0f / dv;
    float myLj = row[j] * rinv;
    row[j] = myLj;
    #pragma unroll
    for (int c = j + 1; c < 64; ++c)
      row[c] = fmaf(-myLj, __shfl(myLj, c), row[c]);
  }
  #pragma unroll
  for (int c = 0; c < 64; ++c)
    Llds[lane * 68 + c] = (c <= lane) ? row[c] : 0.f;
  float w[64];
  #pragma unroll
  for (int r = 0; r < 64; ++r) {
    float s = 0.f;
    #pragma unroll
    for (int kk = 0; kk + 4 <= r; kk += 4) {
      float4 lv = *(const float4*)(Llds + r*68 + kk);
      s += lv.x*w[kk] + lv.y*w[kk+1] + lv.z*w[kk+2] + lv.w*w[kk+3];
    }
    #pragma unroll
    for (int kk = r & ~3; kk < r; ++kk) s += Llds[r*68 + kk] * w[kk];
    float rhs = ((r == lane) ? 1.0f : 0.0f) - s;
    w[r] = rhs / Llds[r*68 + r];   // exact 0 for r < lane
  }
  #pragma unroll
  for (int r = 0; r < 64; ++r) {
    Mk[(size_t)(p0 + r)*DIM + p0 + lane] = w[r];
    Wk[(size_t)(p0 + r)*DIM + p0 + lane] = f2bf(w[r]);
    invT[lane*68 + r] = w[r];   // invT[m][c] = inv[c][m]  (m=lane, c=r)
  }
}

// Whole per-class factorization + inverse sweep in ONE workgroup (grid=NCLS).
// LDS-resident trailing panel: panT[m][i] = L_trail[i][m], stride 452.
// Per panel p: {wave0: fdiag(p) || waves1-3: stage panel A^T} -> trsm (in-place
// panT) -> syrk (both operands LDS) -> sweeprow (panT space reused as scratch).
__global__ __launch_bounds__(256) void factor_kernel(float* __restrict__ M,
                                                     short* __restrict__ Wb) {
  __shared__ float panT[64 * 452];   // 115712 B
  __shared__ float invT[64 * 68];    //  17408 B
  __shared__ float TB[64 * 68];      //  17408 B (fdiag scratch)
  float* Mk = M + (size_t)blockIdx.x * DD;
  short* Wk = Wb + (size_t)blockIdx.x * DD;
  const int tid = threadIdx.x, wv = tid >> 6;
  const int ty = tid >> 4, tx = tid & 15;
  const int sr = tid >> 2, sq = (tid & 3) << 4;

  for (int p = 0; p < 8; ++p) {
    const int p0 = p << 6;
    const int n = 7 - p;
    const int H = n << 6;
    __syncthreads();   // prior panel fully done (incl. global writes)
    if (wv == 0) {
      fdiag_dev(Mk, Wk, p0, tid, TB, invT);
    } else if (n > 0) {
      // stage panT[m][i] = M[p0+64+i][p0+m]  (trailing blocks of column p)
      for (int it = tid - 64; it < (n << 8); it += 192) {
        int i = it % H;
        int c16 = (it / H) << 4;
        const float* src = Mk + (size_t)(p0 + 64 + i) * DIM + p0 + c16;
        float4 v0 = *(const float4*)(src + 0);
        float4 v1 = *(const float4*)(src + 4);
        float4 v2 = *(const float4*)(src + 8);
        float4 v3 = *(const float4*)(src + 12);
        float* dst = panT + i;
        dst[(c16+ 0)*452]=v0.x; dst[(c16+ 1)*452]=v0.y; dst[(c16+ 2)*452]=v0.z; dst[(c16+ 3)*452]=v0.w;
        dst[(c16+ 4)*452]=v1.x; dst[(c16+ 5)*452]=v1.y; dst[(c16+ 6)*452]=v1.z; dst[(c16+ 7)*452]=v1.w;
        dst[(c16+ 8)*452]=v2.x; dst[(c16+ 9)*452]=v2.y; dst[(c16+10)*452]=v2.z; dst[(c16+11)*452]=v2.w;
        dst[(c16+12)*452]=v3.x; dst[(c16+13)*452]=v3.y; dst[(c16+14)*452]=v3.z; dst[(c16+15)*452]=v3.w;
      }
    }
    __syncthreads();
    // ---- TRSM: for each trailing block, L = A * inv^T (A from panT, in-place)
    for (int ib = 0; ib < n; ++ib) {
      const int boff = ib << 6;
      float l2[4][4];
      #pragma unroll
      for (int a2 = 0; a2 < 4; ++a2)
        #pragma unroll
        for (int b2 = 0; b2 < 4; ++b2) l2[a2][b2] = 0.f;
      #pragma unroll 16
      for (int m = 0; m < 64; ++m) {
        float4 av = *(const float4*)(&panT[m*452 + boff + (ty << 2)]);
        float4 bv = *(const float4*)(&invT[m*68 + (tx << 2)]);
        float a4[4] = {av.x, av.y, av.z, av.w};
        float b4[4] = {bv.x, bv.y, bv.z, bv.w};
        #pragma unroll
        for (int ir = 0; ir < 4; ++ir)
          #pragma unroll
          for (int ic = 0; ic < 4; ++ic) l2[ir][ic] += a4[ir] * b4[ic];
      }
      __syncthreads();   // all reads of this block done before overwrite
      #pragma unroll
      for (int q = 0; q < 4; ++q) {
        float4 v; v.x = l2[q][0]; v.y = l2[q][1]; v.z = l2[q][2]; v.w = l2[q][3];
        *(float4*)(Mk + (size_t)(p0 + 64 + boff + (ty << 2) + q)*DIM + p0 + (tx << 2)) = v;
        #pragma unroll
        for (int cc = 0; cc < 4; ++cc)
          panT[((tx << 2) + cc)*452 + boff + (ty << 2) + q] = l2[q][cc];
      }
    }
    __syncthreads();   // panT now holds L^T of the whole panel
    // ---- SYRK: all trailing pairs, operands from LDS, C in global
    for (int bi = 0; bi < n; ++bi) {
      for (int bj = 0; bj <= bi; ++bj) {
        float* cb = Mk + (size_t)(p0 + 64 + (bi << 6) + (ty << 2))*DIM
                       + p0 + 64 + (bj << 6) + (tx << 2);
        float4 c0 = *(const float4*)(cb + 0*DIM);
        float4 c1 = *(const float4*)(cb + 1*DIM);
        float4 c2 = *(const float4*)(cb + 2*DIM);
        float4 c3 = *(const float4*)(cb + 3*DIM);
        float acc[4][4];
        #pragma unroll
        for (int a2 = 0; a2 < 4; ++a2)
          #pragma unroll
          for (int b2 = 0; b2 < 4; ++b2) acc[a2][b2] = 0.f;
        const int oi = bi << 6, oj = bj << 6;
        #pragma unroll 16
        for (int m = 0; m < 64; ++m) {
          float4 av = *(const float4*)(&panT[m*452 + oi + (ty << 2)]);
          float4 bv = *(const float4*)(&panT[m*452 + oj + (tx << 2)]);
          float a4[4] = {av.x, av.y, av.z, av.w};
          float b4[4] = {bv.x, bv.y, bv.z, bv.w};
          #pragma unroll
          for (int ir = 0; ir < 4; ++ir)
            #pragma unroll
            for (int ic = 0; ic < 4; ++ic) acc[ir][ic] += a4[ir] * b4[ic];
        }
        c0.x -= acc[0][0]; c0.y -= acc[0][1]; c0.z -= acc[0][2]; c0.w -= acc[0][3];
        c1.x -= acc[1][0]; c1.y -= acc[1][1]; c1.z -= acc[1][2]; c1.w -= acc[1][3];
        c2.x -= acc[2][0]; c2.y -= acc[2][1]; c2.z -= acc[2][2]; c2.w -= acc[2][3];
        c3.x -= acc[3][0]; c3.y -= acc[3][1]; c3.z -= acc[3][2]; c3.w -= acc[3][3];
        *(float4*)(cb + 0*DIM) = c0;
        *(float4*)(cb + 1*DIM) = c1;
        *(float4*)(cb + 2*DIM) = c2;
        *(float4*)(cb + 3*DIM) = c3;
      }
    }
    // ---- sweeprow: W_pj = -W_pp * sum_{k=j}^{p-1} L_pk W_kj  (j < p)
    // scratch: panT regions 0..3 (panel data dead after syrk)
    for (int j = 0; j < p; ++j) {
      __syncthreads();   // previous j finalize reads / syrk panT reads done
      auto stageLW = [&](int k, int buf) {
        const float* a = Mk + (size_t)(p0 + sr)*DIM + (k << 6) + sq;        // L_pk
        const float* b = Mk + (size_t)((j << 6) + sr)*DIM + (k << 6) + sq;  // W_kj
        #pragma unroll
        for (int t4 = 0; t4 < 4; ++t4) {
          float4 va = *(const float4*)(a + 4*t4);
          panT[buf*4352 + (sq+4*t4+0)*68+sr]=va.x;
          panT[buf*4352 + (sq+4*t4+1)*68+sr]=va.y;
          panT[buf*4352 + (sq+4*t4+2)*68+sr]=va.z;
          panT[buf*4352 + (sq+4*t4+3)*68+sr]=va.w;
          *(float4*)(&panT[(2+buf)*4352 + sr*68 + sq + 4*t4]) = *(const float4*)(b + 4*t4);
        }
      };
      float acc[4][4];
      #pragma unroll
      for (int a = 0; a < 4; ++a)
        #pragma unroll
        for (int b = 0; b < 4; ++b) acc[a][b] = 0.f;
      stageLW(j, 0);
      __syncthreads();
      int cur = 0;
      for (int k = j; k < p; ++k) {
        if (k + 1 < p) stageLW(k + 1, cur ^ 1);
        #pragma unroll 16
        for (int m = 0; m < 64; ++m) {
          float4 av = *(const float4*)(&panT[cur*4352 + m*68 + (ty << 2)]);
          float4 bv = *(const float4*)(&panT[(2+cur)*4352 + m*68 + (tx << 2)]);
          float a4[4] = {av.x, av.y, av.z, av.w};
          float b4[4] = {bv.x, bv.y, bv.z, bv.w};
          #pragma unroll
          for (int ir = 0; ir < 4; ++ir)
            #pragma unroll
            for (int ic = 0; ic < 4; ++ic) acc[ir][ic] += a4[ir] * b4[ic];
        }
        __syncthreads();
        cur ^= 1;
      }
      // S -> region 2 ; finalize with invT as A-operand
      #pragma unroll
      for (int q = 0; q < 4; ++q) {
        float4 v; v.x = acc[q][0]; v.y = acc[q][1]; v.z = acc[q][2]; v.w = acc[q][3];
        *(float4*)(&panT[2*4352 + ((ty << 2) + q)*68 + (tx << 2)]) = v;
      }
      __syncthreads();
      float r2[4][4];
      #pragma unroll
      for (int a = 0; a < 4; ++a)
        #pragma unroll
        for (int b = 0; b < 4; ++b) r2[a][b] = 0.f;
      #pragma unroll 16
      for (int m = 0; m < 64; ++m) {
        float4 av = *(const float4*)(&invT[m*68 + (ty << 2)]);        // W_pp[r][m]
        float4 bv = *(const float4*)(&panT[2*4352 + m*68 + (tx << 2)]);
        float a4[4] = {av.x, av.y, av.z, av.w};
        float b4[4] = {bv.x, bv.y, bv.z, bv.w};
        #pragma unroll
        for (int ir = 0; ir < 4; ++ir)
          #pragma unroll
          for (int ic = 0; ic < 4; ++ic) r2[ir][ic] += a4[ir] * b4[ic];
      }
      #pragma unroll
      for (int q = 0; q < 4; ++q) {
        int a = (ty << 2) + q;
        float4 v; v.x = -r2[q][0]; v.y = -r2[q][1]; v.z = -r2[q][2]; v.w = -r2[q][3];
        *(float4*)(Mk + (size_t)((j << 6) + a)*DIM + p0 + (tx << 2)) = v;   // upper (j,p)
        s16x4 h;
        h[0] = f2bf(v.x); h[1] = f2bf(v.y); h[2] = f2bf(v.z); h[3] = f2bf(v.w);
        *(s16x4*)(Wk + (size_t)(p0 + a)*DIM + (j << 6) + (tx << 2)) = h;    // bf16 (p,j)
      }
    }
  }
}

// scores via bf16 MFMA. W tiles staged via global_load_lds into a 4-buffer
// ring, depth-2 pipeline with counted vmcnt + raw barriers (T3+T4).
__global__ __launch_bounds__(256) void score_kernel(const float* __restrict__ X,
                                                    const float* __restrict__ muK,
                                                    const float* __restrict__ cK,
                                                    const short* __restrict__ W,
                                                    const float* __restrict__ aux,
                                                    float* __restrict__ out) {
  __shared__ __align__(16) char WB4[4][8192];
  __shared__ float sred[4];
  int bid = blockIdx.x;
  int wg = ((bid & 7) * 400) + (bid >> 3);   // XCD swizzle (3200 = 8*400)
  int kc = wg >> 5;
  int n0 = (wg & 31) << 6;
  int tid = threadIdx.x;
  int lane = tid & 63, wv = tid >> 6;
  const short* Wk = W + (size_t)kc * DD;
  const float* mu = muK + (size_t)kc * DIM;
  int r16 = lane & 15;
  int k8 = (lane >> 4) << 3;
  int arow = (wv << 4) + r16;

  int lrow = lane >> 3;
  int lcolel = ((lane & 7) ^ lrow) << 3;

  constexpr int SJT[36] = {0,1,1, 2,3,2,3,2,3,3, 4,5,4,5,4,5,4,5,4,5,5,
                           6,7,6,7,6,7,6,7,6,7,6,7,6,7,7};
  constexpr int SDC[36] = {0,0,1, 0,0,1,1,2,2,3, 0,0,1,1,2,2,3,3,4,4,5,
                           0,0,1,1,2,2,3,3,4,4,5,5,6,6,7};

  bf16x8 af[8][2];
  #pragma unroll
  for (int dc = 0; dc < 8; ++dc) {
    #pragma unroll
    for (int ks = 0; ks < 2; ++ks) {
      int col = (dc << 6) + (ks << 5) + k8;
      const float* xp = X + (size_t)(n0 + arow)*DIM + col;
      float4 x0 = *(const float4*)xp;
      float4 x1 = *(const float4*)(xp + 4);
      float4 m0 = *(const float4*)(mu + col);
      float4 m1 = *(const float4*)(mu + col + 4);
      bf16x8 h;
      h[0]=f2bf(x0.x-m0.x); h[1]=f2bf(x0.y-m0.y); h[2]=f2bf(x0.z-m0.z); h[3]=f2bf(x0.w-m0.w);
      h[4]=f2bf(x1.x-m1.x); h[5]=f2bf(x1.y-m1.y); h[6]=f2bf(x1.z-m1.z); h[7]=f2bf(x1.w-m1.w);
      af[dc][ks] = h;
    }
  }

  auto issue = [&](int s) {
    const int b = s & 3;
    const int rbase = SJT[s] << 6;
    const int cc = (SDC[s] << 6) + lcolel;
    #pragma unroll
    for (int q = 0; q < 2; ++q) {
      const short* g = Wk + (size_t)(rbase + (q << 5) + (wv << 3) + lrow)*DIM + cc;
      __builtin_amdgcn_global_load_lds(
          (const __attribute__((address_space(1))) void*)g,
          (__attribute__((address_space(3))) void*)(WB4[b] + (q << 12) + (wv << 10)),
          16, 0, 0);
    }
  };

  float qp[4] = {0.f, 0.f, 0.f, 0.f};
  f32x4 acc[2][4];
  #pragma unroll
  for (int a = 0; a < 2; ++a)
    #pragma unroll
    for (int jj = 0; jj < 4; ++jj) { acc[a][jj][0]=0.f; acc[a][jj][1]=0.f; acc[a][jj][2]=0.f; acc[a][jj][3]=0.f; }

  issue(0);
  issue(1);
  #pragma unroll
  for (int s = 0; s < 36; ++s) {
    const int jt = SJT[s], dc = SDC[s];
    if (s + 2 < 36) issue(s + 2);
    if (s < 34)      asm volatile("s_waitcnt vmcnt(4)" ::: "memory");
    else if (s == 34) asm volatile("s_waitcnt vmcnt(2)" ::: "memory");
    else              asm volatile("s_waitcnt vmcnt(0)" ::: "memory");
    __builtin_amdgcn_s_barrier();
    __builtin_amdgcn_sched_barrier(0);
    __builtin_amdgcn_s_setprio(1);
    #pragma unroll
    for (int ks = 0; ks < 2; ++ks) {
      #pragma unroll
      for (int jj = 0; jj < 4; ++jj) {
        int brow = (jj << 4) + r16;
        bf16x8 bfr = *(const bf16x8*)((const char*)WB4[s & 3] +
                     (((brow << 7) + (((ks << 5) + k8) << 1)) ^ ((brow & 7) << 4)));
        acc[jt & 1][jj] = __builtin_amdgcn_mfma_f32_16x16x32_bf16(af[dc][ks], bfr, acc[jt & 1][jj], 0, 0, 0);
      }
    }
    __builtin_amdgcn_s_setprio(0);
    if (s == 2 || s == 9 || s == 20 || s == 35) {
      #pragma unroll
      for (int a = 0; a < 2; ++a)
        #pragma unroll
        for (int jj = 0; jj < 4; ++jj)
          #pragma unroll
          for (int r = 0; r < 4; ++r) {
            float y = acc[a][jj][r]; qp[r] += y * y;
            acc[a][jj][r] = 0.f;
          }
    }
  }
  #pragma unroll
  for (int r = 0; r < 4; ++r) {
    qp[r] += __shfl_xor(qp[r], 1);
    qp[r] += __shfl_xor(qp[r], 2);
    qp[r] += __shfl_xor(qp[r], 4);
    qp[r] += __shfl_xor(qp[r], 8);
  }
  {
    float v = (tid < NCLS) ? cK[tid] : 0.f;
    #pragma unroll
    for (int o = 32; o > 0; o >>= 1) v += __shfl_xor(v, o);
    if (lane == 0) sred[wv] = v;
  }
  __syncthreads();
  float sumck = sred[0] + sred[1] + sred[2] + sred[3];
  float ck = cK[kc];
  float base;
  if (ck == 0.f) base = -INFINITY;
  else base = logf(ck) - logf(sumck) - 0.25f * logf(aux[1 + kc]);
  if ((lane & 15) == 0) {
    int nbase = n0 + (wv << 4) + ((lane >> 4) << 2);
    #pragma unroll
    for (int r = 0; r < 4; ++r)
      out[(size_t)(nbase + r)*NCLS + kc] = base - 0.5f * qp[r];
  }
}

extern "C" void kernel_launch(void* const* d_in, const int* in_sizes, int n_in,
                              void* d_out, int out_size, void* d_ws, size_t ws_size,
                              hipStream_t stream) {
  (void)in_sizes; (void)n_in; (void)out_size; (void)ws_size;
  const float* X      = (const float*)d_in[0];
  const float* muK    = (const float*)d_in[1];
  const float* SigmaK = (const float*)d_in[2];
  const float* Sigma  = (const float*)d_in[3];
  const float* cK     = (const float*)d_in[4];
  float* out = (float*)d_out;
  char* ws = (char*)d_ws;
  float* M   = (float*)ws;                                   // 104857600 B
  short* W   = (short*)(ws + (size_t)NCLS * DD * 4);         //  52428800 B
  float* aux = (float*)(ws + (size_t)NCLS * DD * 6);         //       404 B

  (void)hipMemsetAsync(aux, 0, (1 + NCLS) * sizeof(float), stream);
  prep_kernel<<<400, 256, 0, stream>>>(SigmaK, Sigma, M, aux);
  factor_kernel<<<NCLS, 256, 0, stream>>>(M, W);
  score_kernel<<<NCLS * 32, 256, 0, stream>>>(X, muK, cK, W, aux, out);
}

// Round 17
// 764.078 us; speedup vs baseline: 2.5086x; 2.2250x over previous
//
#include <hip/hip_runtime.h>
#include <math.h>

#define DIM 512
#define NCLS 100
#define NS 2048
#define DD (DIM*DIM)
#define SHRINKV 1e-4f

typedef short bf16x8 __attribute__((ext_vector_type(8)));
typedef short s16x4 __attribute__((ext_vector_type(4)));
typedef float f32x4 __attribute__((ext_vector_type(4)));

static __device__ __forceinline__ short f2bf(float f) {
  unsigned int u = __float_as_uint(f);
  u += 0x7FFFu + ((u >> 16) & 1u);   // round-to-nearest-even
  return (short)(u >> 16);
}

// bijective XCD-contiguous remap (m204)
static __device__ __forceinline__ int xcd_swz(int bid, int nwg) {
  int xcd = bid & 7, idx = bid >> 3;
  int q = nwg >> 3, r = nwg & 7;
  return (xcd < r ? xcd * (q + 1) : r * (q + 1) + (xcd - r) * q) + idx;
}

// Build M_k = (1-sh)*(0.5*(SigmaK_k+Sigma)) + sh*I ; accumulate ||RegSigma||_F^2
__global__ __launch_bounds__(256) void prep_kernel(const float* __restrict__ SigmaK,
                                                   const float* __restrict__ Sigma,
                                                   float* __restrict__ M,
                                                   float* __restrict__ aux) {
  int b = blockIdx.x;
  int k = b >> 2, chunk = b & 3;
  const float* Sk = SigmaK + (size_t)k * DD;
  float* Mk = M + (size_t)k * DD;
  int base0 = chunk << 16;
  float fro = 0.f;
  const float oms = 1.0f - SHRINKV;
  for (int it = 0; it < 64; ++it) {
    int idx = base0 + (it << 10) + (threadIdx.x << 2);
    float4 a = *(const float4*)(Sk + idx);
    float4 g = *(const float4*)(Sigma + idx);
    int r = idx >> 9, c = idx & 511;
    float4 reg;
    reg.x = 0.5f*(a.x + g.x); reg.y = 0.5f*(a.y + g.y);
    reg.z = 0.5f*(a.z + g.z); reg.w = 0.5f*(a.w + g.w);
    fro += reg.x*reg.x + reg.y*reg.y + reg.z*reg.z + reg.w*reg.w;
    float4 m;
    m.x = oms*reg.x + ((r == c + 0) ? SHRINKV : 0.f);
    m.y = oms*reg.y + ((r == c + 1) ? SHRINKV : 0.f);
    m.z = oms*reg.z + ((r == c + 2) ? SHRINKV : 0.f);
    m.w = oms*reg.w + ((r == c + 3) ? SHRINKV : 0.f);
    *(float4*)(Mk + idx) = m;
  }
  __shared__ float red[4];
  int lane = threadIdx.x & 63, w = threadIdx.x >> 6;
  for (int o = 32; o > 0; o >>= 1) fro += __shfl_down(fro, o);
  if (lane == 0) red[w] = fro;
  __syncthreads();
  if (threadIdx.x == 0) atomicAdd(&aux[1 + k], red[0] + red[1] + red[2] + red[3]);
}

// Single-wave diag factor + triangular inverse for panel at p0 (no barriers).
static __device__ __forceinline__ void fdiag_dev(float* __restrict__ Mk,
                                                 short* __restrict__ Wk,
                                                 int p0, int lane,
                                                 float* __restrict__ Llds) {
  float row[64];
  const float* src = Mk + (size_t)(p0 + lane) * DIM + p0;
  #pragma unroll
  for (int c4 = 0; c4 < 64; c4 += 4) {
    float4 v = *(const float4*)(src + c4);
    row[c4] = v.x; row[c4+1] = v.y; row[c4+2] = v.z; row[c4+3] = v.w;
  }
  #pragma unroll
  for (int j = 0; j < 64; ++j) {
    float diagv = __shfl(row[j], j);
    float dv = sqrtf(diagv);
    float rinv = 1.0f / dv;
    float myLj = row[j] * rinv;
    row[j] = myLj;
    #pragma unroll
    for (int c = j + 1; c < 64; ++c)
      row[c] = fmaf(-myLj, __shfl(myLj, c), row[c]);
  }
  #pragma unroll
  for (int c = 0; c < 64; ++c)
    Llds[lane * 68 + c] = (c <= lane) ? row[c] : 0.f;
  float w[64];
  #pragma unroll
  for (int r = 0; r < 64; ++r) {
    float s = 0.f;
    #pragma unroll
    for (int kk = 0; kk + 4 <= r; kk += 4) {
      float4 lv = *(const float4*)(Llds + r*68 + kk);
      s += lv.x*w[kk] + lv.y*w[kk+1] + lv.z*w[kk+2] + lv.w*w[kk+3];
    }
    #pragma unroll
    for (int kk = r & ~3; kk < r; ++kk) s += Llds[r*68 + kk] * w[kk];
    float rhs = ((r == lane) ? 1.0f : 0.0f) - s;
    w[r] = rhs / Llds[r*68 + r];   // exact 0 for r < lane
  }
  #pragma unroll
  for (int r = 0; r < 64; ++r) {
    Mk[(size_t)(p0 + r)*DIM + p0 + lane] = w[r];
    Wk[(size_t)(p0 + r)*DIM + p0 + lane] = f2bf(w[r]);
  }
}

// Standalone fdiag for panel 0. One wave per class.
__global__ __launch_bounds__(64) void fdiag_kernel(float* __restrict__ M,
                                                   short* __restrict__ Wb) {
  __shared__ float Llds[64 * 68];
  fdiag_dev(M + (size_t)blockIdx.x * DD, Wb + (size_t)blockIdx.x * DD,
            0, threadIdx.x, Llds);
}

// TRSM for panel p: L_ip = A_ip * inv(p)^T. One WG per (class, i).
// The i==p+1 WG additionally folds the syrk self-update of block (p+1,p+1).
__global__ __launch_bounds__(256) void trsm_kernel(float* __restrict__ M, int p) {
  __shared__ float TA[64 * 68];
  __shared__ float TB[64 * 68];
  int n = 7 - p;
  int wg = xcd_swz(blockIdx.x, NCLS * n);
  int cls = wg / n, bi = wg % n;
  int i = p + 1 + bi;
  float* Mk = M + (size_t)cls * DD;
  int tid = threadIdx.x;
  int ty = tid >> 4, tx = tid & 15;
  int sr = tid >> 2, sq = (tid & 3) << 4;
  int p0 = p << 6;
  {
    const float* a = Mk + (size_t)((i << 6) + sr)*DIM + p0 + sq;
    const float* b = Mk + (size_t)(p0 + sr)*DIM + p0 + sq;   // inv(p)
    #pragma unroll
    for (int t4 = 0; t4 < 4; ++t4) {
      float4 va = *(const float4*)(a + 4*t4);
      TA[(sq+4*t4+0)*68+sr]=va.x; TA[(sq+4*t4+1)*68+sr]=va.y;
      TA[(sq+4*t4+2)*68+sr]=va.z; TA[(sq+4*t4+3)*68+sr]=va.w;
      float4 vb = *(const float4*)(b + 4*t4);
      TB[(sq+4*t4+0)*68+sr]=vb.x; TB[(sq+4*t4+1)*68+sr]=vb.y;
      TB[(sq+4*t4+2)*68+sr]=vb.z; TB[(sq+4*t4+3)*68+sr]=vb.w;
    }
  }
  __syncthreads();
  float acc[4][4];
  #pragma unroll
  for (int a2 = 0; a2 < 4; ++a2)
    #pragma unroll
    for (int b2 = 0; b2 < 4; ++b2) acc[a2][b2] = 0.f;
  #pragma unroll 16
  for (int m = 0; m < 64; ++m) {
    float4 av = *(const float4*)(TA + m*68 + (ty << 2));
    float4 bv = *(const float4*)(TB + m*68 + (tx << 2));
    float a4[4] = {av.x, av.y, av.z, av.w};
    float b4[4] = {bv.x, bv.y, bv.z, bv.w};
    #pragma unroll
    for (int ir = 0; ir < 4; ++ir)
      #pragma unroll
      for (int ic = 0; ic < 4; ++ic) acc[ir][ic] += a4[ir] * b4[ic];
  }
  #pragma unroll
  for (int q = 0; q < 4; ++q) {
    float4 v; v.x = acc[q][0]; v.y = acc[q][1]; v.z = acc[q][2]; v.w = acc[q][3];
    *(float4*)(Mk + (size_t)((i << 6) + (ty << 2) + q)*DIM + p0 + (tx << 2)) = v;
  }
  if (bi == 0) {   // fold syrk of (p+1,p+1): C -= L*L^T  (L = acc, in-register)
    __syncthreads();   // TA/TB reads done
    #pragma unroll
    for (int q = 0; q < 4; ++q)
      #pragma unroll
      for (int cc = 0; cc < 4; ++cc)
        TA[((tx << 2) + cc)*68 + (ty << 2) + q] = acc[q][cc];   // TA[m][r]=L[r][m]
    __syncthreads();
    float s2[4][4];
    #pragma unroll
    for (int a2 = 0; a2 < 4; ++a2)
      #pragma unroll
      for (int b2 = 0; b2 < 4; ++b2) s2[a2][b2] = 0.f;
    #pragma unroll 16
    for (int m = 0; m < 64; ++m) {
      float4 av = *(const float4*)(TA + m*68 + (ty << 2));
      float4 bv = *(const float4*)(TA + m*68 + (tx << 2));
      float a4[4] = {av.x, av.y, av.z, av.w};
      float b4[4] = {bv.x, bv.y, bv.z, bv.w};
      #pragma unroll
      for (int ir = 0; ir < 4; ++ir)
        #pragma unroll
        for (int ic = 0; ic < 4; ++ic) s2[ir][ic] += a4[ir] * b4[ic];
    }
    int d0 = (p + 1) << 6;
    #pragma unroll
    for (int q = 0; q < 4; ++q) {
      float* dst = Mk + (size_t)(d0 + (ty << 2) + q)*DIM + d0 + (tx << 2);
      float4 v = *(const float4*)dst;
      v.x -= s2[q][0]; v.y -= s2[q][1]; v.z -= s2[q][2]; v.w -= s2[q][3];
      *(float4*)dst = v;
    }
  }
}

// Combined launch for panel p: syrkR(p) (all pairs except (p+1,p+1)) in the
// first NCLS*(T-1) WGs, fdiag(p+1) in the last NCLS WGs (hidden under syrk).
__global__ __launch_bounds__(256) void combo_kernel(float* __restrict__ M,
                                                    short* __restrict__ Wb, int p) {
  __shared__ float TA[64 * 68];
  __shared__ float TB[64 * 68];
  int n = 7 - p;
  int T = n * (n + 1) / 2;
  int nsyrk = NCLS * (T - 1);
  int wg = xcd_swz(blockIdx.x, nsyrk + NCLS);
  int tid = threadIdx.x;
  if (wg >= nsyrk) {   // fdiag(p+1)
    int cls = wg - nsyrk;
    if (tid < 64)
      fdiag_dev(M + (size_t)cls * DD, Wb + (size_t)cls * DD,
                (p + 1) << 6, tid, TA);
    return;
  }
  int cls = wg / (T - 1);
  int t = wg % (T - 1) + 1;   // skip t=0 = (p+1,p+1), folded into trsm
  int bi = 0;
  while (t > bi) { t -= bi + 1; ++bi; }
  int i = p + 1 + bi, j = p + 1 + t;
  float* Mk = M + (size_t)cls * DD;
  int ty = tid >> 4, tx = tid & 15;
  int sr = tid >> 2, sq = (tid & 3) << 4;
  {
    const float* a = Mk + (size_t)((i << 6) + sr)*DIM + (p << 6) + sq;
    const float* b = Mk + (size_t)((j << 6) + sr)*DIM + (p << 6) + sq;
    #pragma unroll
    for (int t4 = 0; t4 < 4; ++t4) {
      float4 va = *(const float4*)(a + 4*t4);
      TA[(sq+4*t4+0)*68+sr]=va.x; TA[(sq+4*t4+1)*68+sr]=va.y;
      TA[(sq+4*t4+2)*68+sr]=va.z; TA[(sq+4*t4+3)*68+sr]=va.w;
      float4 vb = *(const float4*)(b + 4*t4);
      TB[(sq+4*t4+0)*68+sr]=vb.x; TB[(sq+4*t4+1)*68+sr]=vb.y;
      TB[(sq+4*t4+2)*68+sr]=vb.z; TB[(sq+4*t4+3)*68+sr]=vb.w;
    }
  }
  __syncthreads();
  float acc[4][4];
  #pragma unroll
  for (int a = 0; a < 4; ++a)
    #pragma unroll
    for (int b = 0; b < 4; ++b) acc[a][b] = 0.f;
  #pragma unroll 16
  for (int m = 0; m < 64; ++m) {
    float4 av = *(const float4*)(TA + m*68 + (ty << 2));
    float4 bv = *(const float4*)(TB + m*68 + (tx << 2));
    float a4[4] = {av.x, av.y, av.z, av.w};
    float b4[4] = {bv.x, bv.y, bv.z, bv.w};
    #pragma unroll
    for (int ir = 0; ir < 4; ++ir)
      #pragma unroll
      for (int ic = 0; ic < 4; ++ic) acc[ir][ic] += a4[ir] * b4[ic];
  }
  #pragma unroll
  for (int q = 0; q < 4; ++q) {
    float* dst = Mk + (size_t)((i << 6) + (ty << 2) + q)*DIM + (j << 6) + (tx << 2);
    float4 v = *(const float4*)dst;
    v.x -= acc[q][0]; v.y -= acc[q][1]; v.z -= acc[q][2]; v.w -= acc[q][3];
    *(float4*)dst = v;
  }
}

// Column sweep: one WG per (class, column j in 0..6). Double-buffered staging.
// Block order is j-MAJOR, LONGEST FIRST (j=0 has 28 serial GEMM stages, j=6
// has 1): long WGs dispatch first so short ones backfill the tail.
__global__ __launch_bounds__(256) void colsweep_kernel(float* __restrict__ M,
                                                       short* __restrict__ Wb) {
  __shared__ float TL[2][64 * 68];
  __shared__ float TW[2][64 * 68];
  int j = blockIdx.x / NCLS;        // j=0 band first (longest)
  int cls = blockIdx.x % NCLS;
  float* Mk = M + (size_t)cls * DD;
  short* Wk = Wb + (size_t)cls * DD;
  int tid = threadIdx.x;
  int ty = tid >> 4, tx = tid & 15;
  int sr = tid >> 2, sq = (tid & 3) << 4;
  for (int i = j + 1; i < 8; ++i) {
    auto stageLW = [&](int k, int buf) {
      const float* a = Mk + (size_t)((i << 6) + sr)*DIM + (k << 6) + sq;
      const float* b = Mk + (size_t)((j << 6) + sr)*DIM + (k << 6) + sq;
      #pragma unroll
      for (int t4 = 0; t4 < 4; ++t4) {
        float4 va = *(const float4*)(a + 4*t4);
        TL[buf][(sq+4*t4+0)*68+sr]=va.x; TL[buf][(sq+4*t4+1)*68+sr]=va.y;
        TL[buf][(sq+4*t4+2)*68+sr]=va.z; TL[buf][(sq+4*t4+3)*68+sr]=va.w;
        *(float4*)(TW[buf] + sr*68 + sq + 4*t4) = *(const float4*)(b + 4*t4);
      }
    };
    float acc[4][4];
    #pragma unroll
    for (int a = 0; a < 4; ++a)
      #pragma unroll
      for (int b = 0; b < 4; ++b) acc[a][b] = 0.f;
    stageLW(j, 0);
    __syncthreads();
    int cur = 0;
    for (int k = j; k < i; ++k) {
      if (k + 1 < i) stageLW(k + 1, cur ^ 1);   // overlaps GEMM below
      #pragma unroll 16
      for (int m = 0; m < 64; ++m) {
        float4 av = *(const float4*)(TL[cur] + m*68 + (ty << 2));
        float4 bv = *(const float4*)(TW[cur] + m*68 + (tx << 2));
        float a4[4] = {av.x, av.y, av.z, av.w};
        float b4[4] = {bv.x, bv.y, bv.z, bv.w};
        #pragma unroll
        for (int ir = 0; ir < 4; ++ir)
          #pragma unroll
          for (int ic = 0; ic < 4; ++ic) acc[ir][ic] += a4[ir] * b4[ic];
      }
      __syncthreads();
      cur ^= 1;
    }
    // finalize: S -> TW[0], W_ii^T -> TL[0]
    #pragma unroll
    for (int q = 0; q < 4; ++q) {
      float4 v; v.x = acc[q][0]; v.y = acc[q][1]; v.z = acc[q][2]; v.w = acc[q][3];
      *(float4*)(TW[0] + ((ty << 2) + q)*68 + (tx << 2)) = v;
    }
    {
      const float* a = Mk + (size_t)((i << 6) + sr)*DIM + (i << 6) + sq;
      #pragma unroll
      for (int t4 = 0; t4 < 4; ++t4) {
        float4 va = *(const float4*)(a + 4*t4);
        TL[0][(sq+4*t4+0)*68+sr]=va.x; TL[0][(sq+4*t4+1)*68+sr]=va.y;
        TL[0][(sq+4*t4+2)*68+sr]=va.z; TL[0][(sq+4*t4+3)*68+sr]=va.w;
      }
    }
    __syncthreads();
    float r2[4][4];
    #pragma unroll
    for (int a = 0; a < 4; ++a)
      #pragma unroll
      for (int b = 0; b < 4; ++b) r2[a][b] = 0.f;
    #pragma unroll 16
    for (int m = 0; m < 64; ++m) {
      float4 av = *(const float4*)(TL[0] + m*68 + (ty << 2));
      float4 bv = *(const float4*)(TW[0] + m*68 + (tx << 2));
      float a4[4] = {av.x, av.y, av.z, av.w};
      float b4[4] = {bv.x, bv.y, bv.z, bv.w};
      #pragma unroll
      for (int ir = 0; ir < 4; ++ir)
        #pragma unroll
        for (int ic = 0; ic < 4; ++ic) r2[ir][ic] += a4[ir] * b4[ic];
    }
    #pragma unroll
    for (int q = 0; q < 4; ++q) {
      int a = (ty << 2) + q;
      float4 v; v.x = -r2[q][0]; v.y = -r2[q][1]; v.z = -r2[q][2]; v.w = -r2[q][3];
      *(float4*)(Mk + (size_t)((j << 6) + a)*DIM + (i << 6) + (tx << 2)) = v;
      s16x4 h;
      h[0] = f2bf(v.x); h[1] = f2bf(v.y); h[2] = f2bf(v.z); h[3] = f2bf(v.w);
      *(s16x4*)(Wk + (size_t)((i << 6) + a)*DIM + (j << 6) + (tx << 2)) = h;
    }
    __syncthreads();   // buffers free for next i
  }
}

// scores via bf16 MFMA. W tiles staged via global_load_lds into a 4-buffer
// ring, depth-2 pipeline with counted vmcnt + raw barriers (T3+T4).
__global__ __launch_bounds__(256) void score_kernel(const float* __restrict__ X,
                                                    const float* __restrict__ muK,
                                                    const float* __restrict__ cK,
                                                    const short* __restrict__ W,
                                                    const float* __restrict__ aux,
                                                    float* __restrict__ out) {
  __shared__ __align__(16) char WB4[4][8192];
  __shared__ float sred[4];
  int bid = blockIdx.x;
  int wg = ((bid & 7) * 400) + (bid >> 3);   // XCD swizzle (3200 = 8*400)
  int kc = wg >> 5;
  int n0 = (wg & 31) << 6;
  int tid = threadIdx.x;
  int lane = tid & 63, wv = tid >> 6;
  const short* Wk = W + (size_t)kc * DD;
  const float* mu = muK + (size_t)kc * DIM;
  int r16 = lane & 15;
  int k8 = (lane >> 4) << 3;
  int arow = (wv << 4) + r16;

  int lrow = lane >> 3;
  int lcolel = ((lane & 7) ^ lrow) << 3;

  constexpr int SJT[36] = {0,1,1, 2,3,2,3,2,3,3, 4,5,4,5,4,5,4,5,4,5,5,
                           6,7,6,7,6,7,6,7,6,7,6,7,6,7,7};
  constexpr int SDC[36] = {0,0,1, 0,0,1,1,2,2,3, 0,0,1,1,2,2,3,3,4,4,5,
                           0,0,1,1,2,2,3,3,4,4,5,5,6,6,7};

  bf16x8 af[8][2];
  #pragma unroll
  for (int dc = 0; dc < 8; ++dc) {
    #pragma unroll
    for (int ks = 0; ks < 2; ++ks) {
      int col = (dc << 6) + (ks << 5) + k8;
      const float* xp = X + (size_t)(n0 + arow)*DIM + col;
      float4 x0 = *(const float4*)xp;
      float4 x1 = *(const float4*)(xp + 4);
      float4 m0 = *(const float4*)(mu + col);
      float4 m1 = *(const float4*)(mu + col + 4);
      bf16x8 h;
      h[0]=f2bf(x0.x-m0.x); h[1]=f2bf(x0.y-m0.y); h[2]=f2bf(x0.z-m0.z); h[3]=f2bf(x0.w-m0.w);
      h[4]=f2bf(x1.x-m1.x); h[5]=f2bf(x1.y-m1.y); h[6]=f2bf(x1.z-m1.z); h[7]=f2bf(x1.w-m1.w);
      af[dc][ks] = h;
    }
  }

  auto issue = [&](int s) {
    const int b = s & 3;
    const int rbase = SJT[s] << 6;
    const int cc = (SDC[s] << 6) + lcolel;
    #pragma unroll
    for (int q = 0; q < 2; ++q) {
      const short* g = Wk + (size_t)(rbase + (q << 5) + (wv << 3) + lrow)*DIM + cc;
      __builtin_amdgcn_global_load_lds(
          (const __attribute__((address_space(1))) void*)g,
          (__attribute__((address_space(3))) void*)(WB4[b] + (q << 12) + (wv << 10)),
          16, 0, 0);
    }
  };

  float qp[4] = {0.f, 0.f, 0.f, 0.f};
  f32x4 acc[2][4];
  #pragma unroll
  for (int a = 0; a < 2; ++a)
    #pragma unroll
    for (int jj = 0; jj < 4; ++jj) { acc[a][jj][0]=0.f; acc[a][jj][1]=0.f; acc[a][jj][2]=0.f; acc[a][jj][3]=0.f; }

  issue(0);
  issue(1);
  #pragma unroll
  for (int s = 0; s < 36; ++s) {
    const int jt = SJT[s], dc = SDC[s];
    if (s + 2 < 36) issue(s + 2);
    if (s < 34)      asm volatile("s_waitcnt vmcnt(4)" ::: "memory");
    else if (s == 34) asm volatile("s_waitcnt vmcnt(2)" ::: "memory");
    else              asm volatile("s_waitcnt vmcnt(0)" ::: "memory");
    __builtin_amdgcn_s_barrier();
    __builtin_amdgcn_sched_barrier(0);
    __builtin_amdgcn_s_setprio(1);
    #pragma unroll
    for (int ks = 0; ks < 2; ++ks) {
      #pragma unroll
      for (int jj = 0; jj < 4; ++jj) {
        int brow = (jj << 4) + r16;
        bf16x8 bfr = *(const bf16x8*)((const char*)WB4[s & 3] +
                     (((brow << 7) + (((ks << 5) + k8) << 1)) ^ ((brow & 7) << 4)));
        acc[jt & 1][jj] = __builtin_amdgcn_mfma_f32_16x16x32_bf16(af[dc][ks], bfr, acc[jt & 1][jj], 0, 0, 0);
      }
    }
    __builtin_amdgcn_s_setprio(0);
    if (s == 2 || s == 9 || s == 20 || s == 35) {
      #pragma unroll
      for (int a = 0; a < 2; ++a)
        #pragma unroll
        for (int jj = 0; jj < 4; ++jj)
          #pragma unroll
          for (int r = 0; r < 4; ++r) {
            float y = acc[a][jj][r]; qp[r] += y * y;
            acc[a][jj][r] = 0.f;
          }
    }
  }
  #pragma unroll
  for (int r = 0; r < 4; ++r) {
    qp[r] += __shfl_xor(qp[r], 1);
    qp[r] += __shfl_xor(qp[r], 2);
    qp[r] += __shfl_xor(qp[r], 4);
    qp[r] += __shfl_xor(qp[r], 8);
  }
  {
    float v = (tid < NCLS) ? cK[tid] : 0.f;
    #pragma unroll
    for (int o = 32; o > 0; o >>= 1) v += __shfl_xor(v, o);
    if (lane == 0) sred[wv] = v;
  }
  __syncthreads();
  float sumck = sred[0] + sred[1] + sred[2] + sred[3];
  float ck = cK[kc];
  float base;
  if (ck == 0.f) base = -INFINITY;
  else base = logf(ck) - logf(sumck) - 0.25f * logf(aux[1 + kc]);
  if ((lane & 15) == 0) {
    int nbase = n0 + (wv << 4) + ((lane >> 4) << 2);
    #pragma unroll
    for (int r = 0; r < 4; ++r)
      out[(size_t)(nbase + r)*NCLS + kc] = base - 0.5f * qp[r];
  }
}

extern "C" void kernel_launch(void* const* d_in, const int* in_sizes, int n_in,
                              void* d_out, int out_size, void* d_ws, size_t ws_size,
                              hipStream_t stream) {
  (void)in_sizes; (void)n_in; (void)out_size; (void)ws_size;
  const float* X      = (const float*)d_in[0];
  const float* muK    = (const float*)d_in[1];
  const float* SigmaK = (const float*)d_in[2];
  const float* Sigma  = (const float*)d_in[3];
  const float* cK     = (const float*)d_in[4];
  float* out = (float*)d_out;
  char* ws = (char*)d_ws;
  float* M   = (float*)ws;                                   // 104857600 B
  short* W   = (short*)(ws + (size_t)NCLS * DD * 4);         //  52428800 B
  float* aux = (float*)(ws + (size_t)NCLS * DD * 6);         //       404 B

  (void)hipMemsetAsync(aux, 0, (1 + NCLS) * sizeof(float), stream);
  prep_kernel<<<400, 256, 0, stream>>>(SigmaK, Sigma, M, aux);
  fdiag_kernel<<<NCLS, 64, 0, stream>>>(M, W);               // inv(0)
  for (int p = 0; p < 7; ++p) {
    int n = 7 - p;
    int T = n * (n + 1) / 2;
    trsm_kernel<<<NCLS * n, 256, 0, stream>>>(M, p);         // + (p+1,p+1) fold
    combo_kernel<<<NCLS * (T - 1) + NCLS, 256, 0, stream>>>(M, W, p);  // syrkR ∥ fdiag(p+1)
  }
  colsweep_kernel<<<NCLS * 7, 256, 0, stream>>>(M, W);
  score_kernel<<<NCLS * 32, 256, 0, stream>>>(X, muK, cK, W, aux, out);
}